// Round 6
// baseline (480.828 us; speedup 1.0000x reference)
//
#include <hip/hip_runtime.h>
#include <math.h>

#define DIMC 512
#define VDIM 256
#define NVARS 320
#define NTOK 32768
#define NELEM (NTOK*DIMC)       // 16777216
#define IDX_OFF NELEM
#define PPL_OFF (NELEM + NTOK*2)
#define KM_OFF (PPL_OFF + 1)

// ws layout: doubles first: dsum[32] (double idx 0..32), dssq[32] (double idx 32..64)
//   == float offsets [0..128). Then float area:
#define OFF_MU   128   // 32 f32
#define OFF_RSTD 160   // 32 f32
#define OFF_LOSS 192   // 1 f32
#define OFF_ESQ  256   // 640 f32 -> [256,896)
#define OFF_HIST 1024  // 640 i32 -> [1024,1664)
#define WS_ZERO_FLOATS 1664

// XOR-swizzled LDS index: conceptual [k][col], physical col4' = col4 ^ (k>>2)
__device__ __forceinline__ int sw128(int k, int col) {
    return k * 128 + ((((col >> 2) ^ (k >> 2)) & 31) << 2) + (col & 3);
}

__global__ void k_init(float* ws) {
    int i = blockIdx.x * 256 + threadIdx.x;
    if (i < WS_ZERO_FLOATS) ws[i] = 0.0f;
}

// e_sq[v*2+g] = sum_d emb[v][g][d]^2, fp64 accumulate -> correctly-rounded f32
__global__ void k_esq(const float* __restrict__ emb, float* ws) {
    int wave = blockIdx.x * 4 + (threadIdx.x >> 6);
    int lane = threadIdx.x & 63;
    const float* p = emb + (size_t)wave * VDIM;
    double s = 0.0;
    for (int j = lane; j < VDIM; j += 64) { double v = (double)p[j]; s += v * v; }
    for (int off = 32; off; off >>= 1) s += __shfl_down(s, off);
    if (lane == 0) ws[OFF_ESQ + wave] = (float)s;
}

// y_t = (x @ W^T)^T per group: writes y_t[g*256+o][tok] (transposed!) into `yt`.
// Tile 128 tok x 128 o, K=256 in 64-chunks, fused GN stats (fp64 atomics).
__global__ __launch_bounds__(256, 2) void k_gemm(const float* __restrict__ x,
                                                 const float* __restrict__ w,
                                                 float* __restrict__ yt, float* ws) {
    __shared__ float As[64 * 128];   // swizzled [k][tok]
    __shared__ float Ws[64 * 128];   // swizzled [k][o]
    __shared__ double red1[256];
    __shared__ double red2[256];
    const int tid = threadIdx.x;
    const int tx = tid & 15, ty = tid >> 4;
    const int tok0 = blockIdx.x * 128;
    const int o0 = blockIdx.y * 128;
    const int g = blockIdx.z;
    const int b = tok0 >> 11;

    float acc[8][8];
#pragma unroll
    for (int i = 0; i < 8; i++)
#pragma unroll
        for (int j = 0; j < 8; j++) acc[i][j] = 0.0f;

    for (int kc = 0; kc < 4; kc++) {
        __syncthreads();
#pragma unroll
        for (int it = 0; it < 8; it++) {
            const int tok = ty + 16 * it;
            float4 v = *(const float4*)(x + (size_t)(tok0 + tok) * DIMC + g * VDIM + kc * 64 + tx * 4);
            As[sw128(tx * 4 + 0, tok)] = v.x; As[sw128(tx * 4 + 1, tok)] = v.y;
            As[sw128(tx * 4 + 2, tok)] = v.z; As[sw128(tx * 4 + 3, tok)] = v.w;
        }
#pragma unroll
        for (int it = 0; it < 8; it++) {
            const int o = ty + 16 * it;
            float4 v = *(const float4*)(w + (size_t)(g * 256 + o0 + o) * 256 + kc * 64 + tx * 4);
            Ws[sw128(tx * 4 + 0, o)] = v.x; Ws[sw128(tx * 4 + 1, o)] = v.y;
            Ws[sw128(tx * 4 + 2, o)] = v.z; Ws[sw128(tx * 4 + 3, o)] = v.w;
        }
        __syncthreads();
        const float4* A4 = (const float4*)As;
        const float4* W4 = (const float4*)Ws;
#pragma unroll 4
        for (int k = 0; k < 64; k++) {
            const int kk = k >> 2;
            float4 a0 = A4[k * 32 + ((2 * ty) ^ kk)];
            float4 a1 = A4[k * 32 + ((2 * ty + 1) ^ kk)];
            float4 b0 = W4[k * 32 + (tx ^ kk)];
            float4 b1 = W4[k * 32 + ((16 + tx) ^ kk)];
            float av[8] = {a0.x, a0.y, a0.z, a0.w, a1.x, a1.y, a1.z, a1.w};
            float bv[8] = {b0.x, b0.y, b0.z, b0.w, b1.x, b1.y, b1.z, b1.w};
#pragma unroll
            for (int i = 0; i < 8; i++)
#pragma unroll
                for (int j = 0; j < 8; j++) acc[i][j] = fmaf(av[i], bv[j], acc[i][j]);
        }
    }
    // epilogue: fp64 stats + transposed y_t stores (8 toks contiguous per o)
    double s1 = 0.0, s2 = 0.0;
#pragma unroll
    for (int i = 0; i < 8; i++)
#pragma unroll
        for (int j = 0; j < 8; j++) {
            s1 += (double)acc[i][j];
            s2 += (double)acc[i][j] * acc[i][j];
        }
#pragma unroll
    for (int j = 0; j < 8; j++) {
        const int o = o0 + ((j < 4) ? (tx * 4 + j) : (64 + tx * 4 + (j - 4)));
        float4 lo = make_float4(acc[0][j], acc[1][j], acc[2][j], acc[3][j]);
        float4 hi = make_float4(acc[4][j], acc[5][j], acc[6][j], acc[7][j]);
        float* p = yt + (size_t)(g * 256 + o) * NTOK + tok0 + ty * 8;
        *(float4*)p = lo;
        *(float4*)(p + 4) = hi;
    }
    red1[tid] = s1; red2[tid] = s2;
    __syncthreads();
    for (int s = 128; s; s >>= 1) {
        if (tid < s) { red1[tid] += red1[tid + s]; red2[tid] += red2[tid + s]; }
        __syncthreads();
    }
    if (tid == 0) {
        double* dws = (double*)ws;
        atomicAdd(&dws[b * 2 + g], red1[0]);
        atomicAdd(&dws[32 + b * 2 + g], red2[0]);
    }
}

__global__ void k_stats(float* ws) {
    int i = threadIdx.x;
    if (i < 32) {
        const double* d = (const double*)ws;
        double mu = d[i] * (1.0 / 524288.0);
        double var = d[32 + i] * (1.0 / 524288.0) - mu * mu;
        float varf = (float)var;
        ws[OFF_MU + i] = (float)mu;
        ws[OFF_RSTD + i] = 1.0f / sqrtf(varf + 1e-5f);
    }
}

// VQ, 2.5 passes over v (128+128+64), tile 128 tok x 128 v, acc[8][8], BK=32.
// Round-6 change vs round-5 (196us, VALU 51%): BK 64->32 so LDS = As 16K +
// Es 16K + misc ~= 35 KB -> 4 blocks/CU = 4 waves/SIMD (was 2). Model from
// R0/R5: LDS read pipe (b128 ~12cy/inst, one unit/CU) vs VALU ratio = 1.5
// -> VALU ceiling 67%; R5 measured 51% because 2 waves/SIMD can't keep both
// pipes fed (R0 with 3 waves/SIMD sat exactly AT its 44% ceiling). Same
// read:FMA ratio, same total reads, double the resident waves.
// Numerics bit-identical to rounds 0-5: same values, same kc-major/k-minor
// (global k ascending 0..255) FMA chain order, d2 = fl(fl(zsq-2*dot)+esq),
// ties -> lowest v, zsq fp64 chain order unchanged, lex-min shfl unchanged.
__global__ __launch_bounds__(256, 4) void k_vq(const float* __restrict__ emb,
                                               const float* __restrict__ gnw,
                                               const float* __restrict__ gnb,
                                               float* out, float* ws) {
    __shared__ float As[32 * 128];   // LINEAR [k][tok]   16 KB
    __shared__ float Es[32 * 128];   // swizzled [k][v]   16 KB
    __shared__ float Gw[256];
    __shared__ float Gb[256];
    __shared__ float zsqs[128];
    __shared__ float lsum[16];

    const int tid = threadIdx.x;
    const int tx = tid & 15, ty = tid >> 4;    // 16 x 16
    const int tok0 = blockIdx.x * 128;
    const int g = blockIdx.y;
    const int b = tok0 >> 11;
    const float mu = ws[OFF_MU + b * 2 + g];
    const float rstd = ws[OFF_RSTD + b * 2 + g];
    int* hist = ((int*)ws) + OFF_HIST;
    const float* yt = out;           // y_t[g*256+k][NTOK]

    // gn affine cache (visible after first __syncthreads of the kc loop)
    Gw[tid] = gnw[g * VDIM + tid];
    Gb[tid] = gnb[g * VDIM + tid];

    // j-linear As staging: float4 slot f = it*256 + tid -> k-row = it*8+skr,
    // tok-quad = st4. y_t reads coalesced (512B runs per k-row).
    const int skr = tid >> 5;        // 0..7
    const int st4 = tid & 31;        // 0..31
    const float* ybase = yt + ((size_t)g * 256 + skr) * NTOK + tok0 + st4 * 4;

    // Es staging maps (BK=32): passes 0/1: 2 thr per v-row, 4 float4 (16 k) each.
    const int evr = tid >> 1;        // v-row 0..127
    const int ekh = tid & 1;         // k-half 0..1
    // pass 2: 4 thr per v-row, 2 float4 (8 k) each.
    const int evr2 = tid >> 2;       // v-row 0..63
    const int ekh2 = tid & 3;        // k-quarter 0..3

    float br[8]; int bv[8]; float zs[8];
#pragma unroll
    for (int i = 0; i < 8; i++) { br[i] = 3.0e38f; bv[i] = 0; }
    double zacc = 0.0;
    float4 pv[4];                    // y_t prefetch registers (+16 VGPR)

#define LOADY(KC) do {                                                         \
    _Pragma("unroll")                                                          \
    for (int it_ = 0; it_ < 4; it_++)                                          \
        pv[it_] = *(const float4*)(ybase + (size_t)((KC) * 32 + it_ * 8) * NTOK); \
} while (0)

#define WRITE_AS(KC) do {                                                      \
    _Pragma("unroll")                                                          \
    for (int it_ = 0; it_ < 4; it_++) {                                        \
        const int kl_ = it_ * 8 + skr;                                         \
        const float gw_ = Gw[(KC) * 32 + kl_];                                 \
        const float gb_ = Gb[(KC) * 32 + kl_];                                 \
        float4 v_ = pv[it_];                                                   \
        float4 z_;                                                             \
        z_.x = fmaf((v_.x - mu) * rstd, gw_, gb_);                             \
        z_.y = fmaf((v_.y - mu) * rstd, gw_, gb_);                             \
        z_.z = fmaf((v_.z - mu) * rstd, gw_, gb_);                             \
        z_.w = fmaf((v_.w - mu) * rstd, gw_, gb_);                             \
        ((float4*)As)[it_ * 256 + tid] = z_;                                   \
    }                                                                          \
} while (0)

    // ---- passes 0,1: v-tiles [0,128) and [128,256), acc[8][8] ----
    for (int pass = 0; pass < 2; pass++) {
        const int vbase = pass * 128;
        float acc[8][8];
#pragma unroll
        for (int i = 0; i < 8; i++)
#pragma unroll
            for (int j = 0; j < 8; j++) acc[i][j] = 0.0f;

        LOADY(0);
        for (int kc = 0; kc < 8; kc++) {
            __syncthreads();
            WRITE_AS(kc);
            // stage Es: 128 v-rows, row-major emb -> swizzled [k][v]
            {
                const float* erow = emb + (size_t)((vbase + evr) * 2 + g) * VDIM + kc * 32 + ekh * 16;
#pragma unroll
                for (int f = 0; f < 4; f++) {
                    float4 e = *(const float4*)(erow + f * 4);
                    const int k0 = ekh * 16 + f * 4;
                    Es[sw128(k0 + 0, evr)] = e.x; Es[sw128(k0 + 1, evr)] = e.y;
                    Es[sw128(k0 + 2, evr)] = e.z; Es[sw128(k0 + 3, evr)] = e.w;
                }
            }
            if (kc < 7) LOADY(kc + 1);   // prefetch next k-chunk
            __syncthreads();
            // zsq (pass 0 only): tok=tid<128, serial k order, fp64, linear reads
            if (pass == 0 && tid < 128) {
                for (int k = 0; k < 32; k++) {
                    float z = As[k * 128 + tid];
                    zacc += (double)z * z;
                }
            }
            // compute: A-reads immediate-offset broadcasts; E XOR hoisted per k4
            const float4* Aty = ((const float4*)As) + 2 * ty;
            const float4* E4 = (const float4*)Es;
#pragma unroll 2
            for (int k4 = 0; k4 < 8; k4++) {
                const float4* Ee = E4 + (tx ^ k4);
#pragma unroll
                for (int m = 0; m < 4; m++) {
                    const int k = k4 * 4 + m;
                    float4 a0 = Aty[k * 32];
                    float4 a1 = Aty[k * 32 + 1];
                    float4 e0 = Ee[k * 32];
                    float4 e1 = Ee[k * 32 + 16];
                    float av[8] = {a0.x, a0.y, a0.z, a0.w, a1.x, a1.y, a1.z, a1.w};
                    float ev[8] = {e0.x, e0.y, e0.z, e0.w, e1.x, e1.y, e1.z, e1.w};
#pragma unroll
                    for (int i = 0; i < 8; i++)
#pragma unroll
                        for (int j = 0; j < 8; j++)
                            acc[i][j] = fmaf(av[i], ev[j], acc[i][j]);
                }
            }
        }
        if (pass == 0) {
            if (tid < 128) zsqs[tid] = (float)zacc;
            __syncthreads();
#pragma unroll
            for (int i = 0; i < 8; i++) zs[i] = zsqs[ty * 8 + i];
        }
        // fold: ascending v within thread (j<4: vbase+tx*4+j; j>=4: vbase+64+tx*4+j-4)
        float esql[8];
#pragma unroll
        for (int j = 0; j < 4; j++) esql[j] = ws[OFF_ESQ + (size_t)(vbase + tx * 4 + j) * 2 + g];
#pragma unroll
        for (int j = 4; j < 8; j++) esql[j] = ws[OFF_ESQ + (size_t)(vbase + 64 + tx * 4 + (j - 4)) * 2 + g];
#pragma unroll
        for (int i = 0; i < 8; i++)
#pragma unroll
            for (int j = 0; j < 8; j++) {
                float t = zs[i] - 2.0f * acc[i][j];
                float d2 = t + esql[j];
                int v = (j < 4) ? (vbase + tx * 4 + j) : (vbase + 64 + tx * 4 + (j - 4));
                if (d2 < br[i]) { br[i] = d2; bv[i] = v; }
            }
    }

    // ---- pass 2: v-tile [256,320), 64 wide, acc[8][4] ----
    {
        float acc[8][4];
#pragma unroll
        for (int i = 0; i < 8; i++)
#pragma unroll
            for (int j = 0; j < 4; j++) acc[i][j] = 0.0f;

        LOADY(0);
        for (int kc = 0; kc < 8; kc++) {
            __syncthreads();
            WRITE_AS(kc);
            // stage Es: 64 v-rows only (cols 0..63; swizzle keeps col4^kk in 0..15)
            {
                const float* erow = emb + (size_t)((256 + evr2) * 2 + g) * VDIM + kc * 32 + ekh2 * 8;
#pragma unroll
                for (int f = 0; f < 2; f++) {
                    float4 e = *(const float4*)(erow + f * 4);
                    const int k0 = ekh2 * 8 + f * 4;
                    Es[sw128(k0 + 0, evr2)] = e.x; Es[sw128(k0 + 1, evr2)] = e.y;
                    Es[sw128(k0 + 2, evr2)] = e.z; Es[sw128(k0 + 3, evr2)] = e.w;
                }
            }
            if (kc < 7) LOADY(kc + 1);
            __syncthreads();
            const float4* Aty = ((const float4*)As) + 2 * ty;
            const float4* E4 = (const float4*)Es;
#pragma unroll 2
            for (int k4 = 0; k4 < 8; k4++) {
                const float4* Ee = E4 + (tx ^ k4);
#pragma unroll
                for (int m = 0; m < 4; m++) {
                    const int k = k4 * 4 + m;
                    float4 a0 = Aty[k * 32];
                    float4 a1 = Aty[k * 32 + 1];
                    float4 e0 = Ee[k * 32];
                    float av[8] = {a0.x, a0.y, a0.z, a0.w, a1.x, a1.y, a1.z, a1.w};
                    float ev[4] = {e0.x, e0.y, e0.z, e0.w};
#pragma unroll
                    for (int i = 0; i < 8; i++)
#pragma unroll
                        for (int j = 0; j < 4; j++)
                            acc[i][j] = fmaf(av[i], ev[j], acc[i][j]);
                }
            }
        }
        float esql[4];
#pragma unroll
        for (int j = 0; j < 4; j++) esql[j] = ws[OFF_ESQ + (size_t)(256 + tx * 4 + j) * 2 + g];
#pragma unroll
        for (int i = 0; i < 8; i++)
#pragma unroll
            for (int j = 0; j < 4; j++) {
                float t = zs[i] - 2.0f * acc[i][j];
                float d2 = t + esql[j];
                int v = 256 + tx * 4 + j;
                if (d2 < br[i]) { br[i] = d2; bv[i] = v; }
            }
    }
#undef LOADY
#undef WRITE_AS

    // cross-thread (tx) lexicographic min, 16-wide shfl
#pragma unroll
    for (int i = 0; i < 8; i++) {
#pragma unroll
        for (int off = 8; off; off >>= 1) {
            float r2 = __shfl_down(br[i], off, 16);
            int v2 = __shfl_down(bv[i], off, 16);
            if (r2 < br[i] || (r2 == br[i] && v2 < bv[i])) { br[i] = r2; bv[i] = v2; }
        }
    }
    float dlocal = 0.0f;
    if (tx == 0) {
#pragma unroll
        for (int i = 0; i < 8; i++) {
            const int tok = ty * 8 + i;
            out[IDX_OFF + (size_t)(tok0 + tok) * 2 + g] = (float)bv[i];
            atomicAdd(&hist[g * 320 + bv[i]], 1);
            dlocal += br[i];
        }
        lsum[ty] = dlocal;
    }
    __syncthreads();
    if (tid == 0) {
        float s = 0.0f;
        for (int t = 0; t < 16; t++) s += lsum[t];
        atomicAdd(&ws[OFF_LOSS], s);
    }
}

// x_out = zq gather: reads idx from out's idx region, overwrites y_t region with zq.
// Separate kernel => global barrier vs k_vq's y_t reads (y_t aliases x_out region).
__global__ __launch_bounds__(256) void k_gather(const float* __restrict__ emb,
                                                float* out) {
    __shared__ int sidx[128];
    const int tid = threadIdx.x;
    const int tok0 = blockIdx.x * 64;
    if (tid < 128) sidx[tid] = (int)out[IDX_OFF + (size_t)tok0 * 2 + tid];
    __syncthreads();
#pragma unroll 4
    for (int it = 0; it < 32; it++) {
        const int j = it * 256 + tid;
        const int tl = j >> 7;           // token within block (0..63)
        const int c4 = j & 127;          // float4 index within row (0..127)
        const int g = c4 >> 6;
        const int v = sidx[tl * 2 + g];
        float4 e = *(const float4*)(emb + (size_t)(v * 2 + g) * VDIM + (c4 & 63) * 4);
        *(float4*)(out + (size_t)(tok0 + tl) * DIMC + c4 * 4) = e;
    }
}

__global__ void k_final(float* out, float* ws) {
    __shared__ float red[512];
    int tid = threadIdx.x;
    int* hist = ((int*)ws) + OFF_HIST;
    float ppl = 0.0f;
    for (int g = 0; g < 2; g++) {
        float term = 0.0f;
        if (tid < 320) {
            float p = (float)hist[g * 320 + tid] * (1.0f / 32768.0f);
            term = p * logf(p + 1e-7f);
        }
        red[tid] = term;
        __syncthreads();
        for (int s = 256; s; s >>= 1) {
            if (tid < s) red[tid] += red[tid + s];
            __syncthreads();
        }
        if (tid == 0) ppl += expf(-red[0]);
        __syncthreads();
    }
    if (tid == 0) {
        out[PPL_OFF] = ppl;
        out[KM_OFF] = 1.25f * ws[OFF_LOSS] / 16777216.0f;
    }
}

extern "C" void kernel_launch(void* const* d_in, const int* in_sizes, int n_in,
                              void* d_out, int out_size, void* d_ws, size_t ws_size,
                              hipStream_t stream) {
    (void)in_sizes; (void)n_in; (void)out_size; (void)ws_size;
    const float* x      = (const float*)d_in[0];
    const float* conv_w = (const float*)d_in[1];
    const float* gn_w   = (const float*)d_in[2];
    const float* gn_b   = (const float*)d_in[3];
    const float* emb    = (const float*)d_in[4];
    float* out = (float*)d_out;
    float* ws  = (float*)d_ws;

    hipLaunchKernelGGL(k_init,   dim3(7),         dim3(256), 0, stream, ws);
    hipLaunchKernelGGL(k_esq,    dim3(160),       dim3(256), 0, stream, emb, ws);
    hipLaunchKernelGGL(k_gemm,   dim3(256, 2, 2), dim3(256), 0, stream, x, conv_w, out, ws);
    hipLaunchKernelGGL(k_stats,  dim3(1),         dim3(64),  0, stream, ws);
    hipLaunchKernelGGL(k_vq,     dim3(256, 2),    dim3(256), 0, stream, emb, gn_w, gn_b, out, ws);
    hipLaunchKernelGGL(k_gather, dim3(512),       dim3(256), 0, stream, emb, out);
    hipLaunchKernelGGL(k_final,  dim3(1),         dim3(512), 0, stream, out, ws);
}

// Round 7
// 387.136 us; speedup vs baseline: 1.2420x; 1.2420x over previous
//
#include <hip/hip_runtime.h>
#include <math.h>

#define DIMC 512
#define VDIM 256
#define NVARS 320
#define NTOK 32768
#define NELEM (NTOK*DIMC)       // 16777216
#define IDX_OFF NELEM
#define PPL_OFF (NELEM + NTOK*2)
#define KM_OFF (PPL_OFF + 1)

// ws layout: doubles first: dsum[32] (double idx 0..32), dssq[32] (double idx 32..64)
//   == float offsets [0..128). Then float area:
#define OFF_MU   128   // 32 f32
#define OFF_RSTD 160   // 32 f32
#define OFF_LOSS 192   // 1 f32
#define OFF_ESQ  256   // 640 f32 -> [256,896)
#define OFF_HIST 1024  // 640 i32 -> [1024,1664)
#define WS_ZERO_FLOATS 1664
// argmin keys: 65536 x u64 at float offset 2048 (byte 8192, 8B-aligned)
#define KEY_OFF 2048
#define WS_NEED_BYTES ((size_t)KEY_OFF*4 + (size_t)65536*8)

// XOR-swizzled LDS index: conceptual [k][col], physical col4' = col4 ^ (k>>2)
__device__ __forceinline__ int sw128(int k, int col) {
    return k * 128 + ((((col >> 2) ^ (k >> 2)) & 31) << 2) + (col & 3);
}

// order-preserving float->uint: u(a) < u(b) <=> a < b (all finite floats)
__device__ __forceinline__ unsigned long long packkey(float d2, int v) {
    unsigned u = __float_as_uint(d2);
    u = (u & 0x80000000u) ? ~u : (u | 0x80000000u);
    return ((unsigned long long)u << 32) | (unsigned)v;
}

__global__ void k_init(float* ws) {
    int i = blockIdx.x * 256 + threadIdx.x;
    if (i < WS_ZERO_FLOATS) ws[i] = 0.0f;
}

// init for the v-split path: zero float area AND set keys to +inf
__global__ void k_init2(float* ws) {
    int i = blockIdx.x * 256 + threadIdx.x;
    if (i < WS_ZERO_FLOATS) ws[i] = 0.0f;
    unsigned long long* keys = (unsigned long long*)(ws + KEY_OFF);
    keys[i] = ~0ULL;                 // grid is exactly 65536 threads
}

// e_sq[v*2+g] = sum_d emb[v][g][d]^2, fp64 accumulate -> correctly-rounded f32
__global__ void k_esq(const float* __restrict__ emb, float* ws) {
    int wave = blockIdx.x * 4 + (threadIdx.x >> 6);
    int lane = threadIdx.x & 63;
    const float* p = emb + (size_t)wave * VDIM;
    double s = 0.0;
    for (int j = lane; j < VDIM; j += 64) { double v = (double)p[j]; s += v * v; }
    for (int off = 32; off; off >>= 1) s += __shfl_down(s, off);
    if (lane == 0) ws[OFF_ESQ + wave] = (float)s;
}

// y_t = (x @ W^T)^T per group: writes y_t[g*256+o][tok] (transposed!) into `yt`.
// Tile 128 tok x 128 o, K=256 in 64-chunks, fused GN stats (fp64 atomics).
__global__ __launch_bounds__(256, 2) void k_gemm(const float* __restrict__ x,
                                                 const float* __restrict__ w,
                                                 float* __restrict__ yt, float* ws) {
    __shared__ float As[64 * 128];   // swizzled [k][tok]
    __shared__ float Ws[64 * 128];   // swizzled [k][o]
    __shared__ double red1[256];
    __shared__ double red2[256];
    const int tid = threadIdx.x;
    const int tx = tid & 15, ty = tid >> 4;
    const int tok0 = blockIdx.x * 128;
    const int o0 = blockIdx.y * 128;
    const int g = blockIdx.z;
    const int b = tok0 >> 11;

    float acc[8][8];
#pragma unroll
    for (int i = 0; i < 8; i++)
#pragma unroll
        for (int j = 0; j < 8; j++) acc[i][j] = 0.0f;

    for (int kc = 0; kc < 4; kc++) {
        __syncthreads();
#pragma unroll
        for (int it = 0; it < 8; it++) {
            const int tok = ty + 16 * it;
            float4 v = *(const float4*)(x + (size_t)(tok0 + tok) * DIMC + g * VDIM + kc * 64 + tx * 4);
            As[sw128(tx * 4 + 0, tok)] = v.x; As[sw128(tx * 4 + 1, tok)] = v.y;
            As[sw128(tx * 4 + 2, tok)] = v.z; As[sw128(tx * 4 + 3, tok)] = v.w;
        }
#pragma unroll
        for (int it = 0; it < 8; it++) {
            const int o = ty + 16 * it;
            float4 v = *(const float4*)(w + (size_t)(g * 256 + o0 + o) * 256 + kc * 64 + tx * 4);
            Ws[sw128(tx * 4 + 0, o)] = v.x; Ws[sw128(tx * 4 + 1, o)] = v.y;
            Ws[sw128(tx * 4 + 2, o)] = v.z; Ws[sw128(tx * 4 + 3, o)] = v.w;
        }
        __syncthreads();
        const float4* A4 = (const float4*)As;
        const float4* W4 = (const float4*)Ws;
#pragma unroll 4
        for (int k = 0; k < 64; k++) {
            const int kk = k >> 2;
            float4 a0 = A4[k * 32 + ((2 * ty) ^ kk)];
            float4 a1 = A4[k * 32 + ((2 * ty + 1) ^ kk)];
            float4 b0 = W4[k * 32 + (tx ^ kk)];
            float4 b1 = W4[k * 32 + ((16 + tx) ^ kk)];
            float av[8] = {a0.x, a0.y, a0.z, a0.w, a1.x, a1.y, a1.z, a1.w};
            float bv[8] = {b0.x, b0.y, b0.z, b0.w, b1.x, b1.y, b1.z, b1.w};
#pragma unroll
            for (int i = 0; i < 8; i++)
#pragma unroll
                for (int j = 0; j < 8; j++) acc[i][j] = fmaf(av[i], bv[j], acc[i][j]);
        }
    }
    // epilogue: fp64 stats + transposed y_t stores (8 toks contiguous per o)
    double s1 = 0.0, s2 = 0.0;
#pragma unroll
    for (int i = 0; i < 8; i++)
#pragma unroll
        for (int j = 0; j < 8; j++) {
            s1 += (double)acc[i][j];
            s2 += (double)acc[i][j] * acc[i][j];
        }
#pragma unroll
    for (int j = 0; j < 8; j++) {
        const int o = o0 + ((j < 4) ? (tx * 4 + j) : (64 + tx * 4 + (j - 4)));
        float4 lo = make_float4(acc[0][j], acc[1][j], acc[2][j], acc[3][j]);
        float4 hi = make_float4(acc[4][j], acc[5][j], acc[6][j], acc[7][j]);
        float* p = yt + (size_t)(g * 256 + o) * NTOK + tok0 + ty * 8;
        *(float4*)p = lo;
        *(float4*)(p + 4) = hi;
    }
    red1[tid] = s1; red2[tid] = s2;
    __syncthreads();
    for (int s = 128; s; s >>= 1) {
        if (tid < s) { red1[tid] += red1[tid + s]; red2[tid] += red2[tid + s]; }
        __syncthreads();
    }
    if (tid == 0) {
        double* dws = (double*)ws;
        atomicAdd(&dws[b * 2 + g], red1[0]);
        atomicAdd(&dws[32 + b * 2 + g], red2[0]);
    }
}

__global__ void k_stats(float* ws) {
    int i = threadIdx.x;
    if (i < 32) {
        const double* d = (const double*)ws;
        double mu = d[i] * (1.0 / 524288.0);
        double var = d[32 + i] * (1.0 / 524288.0) - mu * mu;
        float varf = (float)var;
        ws[OFF_MU + i] = (float)mu;
        ws[OFF_RSTD + i] = 1.0f / sqrtf(varf + 1e-5f);
    }
}

// VQ, v-SPLIT grid: blockIdx.z = vpass {0:v[0,128), 1:v[128,256), 2:v[256,320)}.
// 1536 blocks (vs 512) so the grid can supply 4 blocks/CU (R6 lesson: grid,
// not resources, limited occupancy to 2 blocks/CU). BK=32 -> LDS ~34.5 KB
// (4 blocks/CU); (256,2) launch bounds (R6: (256,4) forced VGPR=64 + spill).
// Cross-block argmin: atomicMin on packed (ordered(d2)<<32 | v) == exact
// lexicographic (d2,v) min == the sequential ascending-v strict-< fold.
// Each block computes zsq locally (identical fp64 chain) so d2 bits are
// identical to rounds 0-6; idx/hist/ppl bit-identical. Loss summation order
// changes (was already non-deterministic float atomics).
__global__ __launch_bounds__(256, 2) void k_vq(const float* __restrict__ emb,
                                               const float* __restrict__ gnw,
                                               const float* __restrict__ gnb,
                                               float* out, float* ws) {
    __shared__ float As[32 * 128];   // LINEAR [k][tok]   16 KB
    __shared__ float Es[32 * 128];   // swizzled [k][v]   16 KB
    __shared__ float Gw[256];
    __shared__ float Gb[256];
    __shared__ float zsqs[128];

    const int tid = threadIdx.x;
    const int tx = tid & 15, ty = tid >> 4;    // 16 x 16
    const int tok0 = blockIdx.x * 128;
    const int g = blockIdx.y;
    const int vpass = blockIdx.z;
    const int b = tok0 >> 11;
    const float mu = ws[OFF_MU + b * 2 + g];
    const float rstd = ws[OFF_RSTD + b * 2 + g];
    const float* yt = out;           // y_t[g*256+k][NTOK]
    const int vbase = vpass * 128;
    const bool full = (vpass < 2);

    Gw[tid] = gnw[g * VDIM + tid];
    Gb[tid] = gnb[g * VDIM + tid];

    // j-linear As staging: float4 slot f = it*256 + tid -> k-row = it*8+skr,
    // tok-quad = st4; y_t reads coalesced (512B runs per k-row).
    const int skr = tid >> 5;        // 0..7
    const int st4 = tid & 31;        // 0..31
    const float* ybase = yt + ((size_t)g * 256 + skr) * NTOK + tok0 + st4 * 4;

    // Es staging maps: full: 2 thr/v-row, 4 float4 (16 k) each; half: 4 thr/row.
    const int evr = tid >> 1;        // v-row 0..127
    const int ekh = tid & 1;         // k-half 0..1
    const int evr2 = tid >> 2;       // v-row 0..63
    const int ekh2 = tid & 3;        // k-quarter 0..3

    float acc[8][8];
#pragma unroll
    for (int i = 0; i < 8; i++)
#pragma unroll
        for (int j = 0; j < 8; j++) acc[i][j] = 0.0f;
    double zacc = 0.0;

    for (int kc = 0; kc < 8; kc++) {
        __syncthreads();
        // ---- stage As: 4 y_t float4 loads -> affine -> linear b128 writes ----
        {
            float4 q[4];
#pragma unroll
            for (int it = 0; it < 4; it++)
                q[it] = *(const float4*)(ybase + (size_t)(kc * 32 + it * 8) * NTOK);
#pragma unroll
            for (int it = 0; it < 4; it++) {
                const int kl = it * 8 + skr;
                const float gw_ = Gw[kc * 32 + kl];
                const float gb_ = Gb[kc * 32 + kl];
                float4 z_;
                z_.x = fmaf((q[it].x - mu) * rstd, gw_, gb_);
                z_.y = fmaf((q[it].y - mu) * rstd, gw_, gb_);
                z_.z = fmaf((q[it].z - mu) * rstd, gw_, gb_);
                z_.w = fmaf((q[it].w - mu) * rstd, gw_, gb_);
                ((float4*)As)[it * 256 + tid] = z_;
            }
        }
        // ---- stage Es for this block's v-tile ----
        if (full) {
            const float* erow = emb + (size_t)((vbase + evr) * 2 + g) * VDIM + kc * 32 + ekh * 16;
#pragma unroll
            for (int f = 0; f < 4; f++) {
                float4 e = *(const float4*)(erow + f * 4);
                const int k0 = ekh * 16 + f * 4;
                Es[sw128(k0 + 0, evr)] = e.x; Es[sw128(k0 + 1, evr)] = e.y;
                Es[sw128(k0 + 2, evr)] = e.z; Es[sw128(k0 + 3, evr)] = e.w;
            }
        } else {
            const float* erow = emb + (size_t)((256 + evr2) * 2 + g) * VDIM + kc * 32 + ekh2 * 8;
#pragma unroll
            for (int f = 0; f < 2; f++) {
                float4 e = *(const float4*)(erow + f * 4);
                const int k0 = ekh2 * 8 + f * 4;
                Es[sw128(k0 + 0, evr2)] = e.x; Es[sw128(k0 + 1, evr2)] = e.y;
                Es[sw128(k0 + 2, evr2)] = e.z; Es[sw128(k0 + 3, evr2)] = e.w;
            }
        }
        __syncthreads();
        // ---- zsq: every block (needed for its d2); serial global-k fp64 chain ----
        if (tid < 128) {
            for (int k = 0; k < 32; k++) {
                float z = As[k * 128 + tid];
                zacc += (double)z * z;
            }
        }
        // ---- compute ----
        const float4* Aty = ((const float4*)As) + 2 * ty;
        const float4* E4 = (const float4*)Es;
        if (full) {
#pragma unroll 2
            for (int k4 = 0; k4 < 8; k4++) {
                const float4* Ee = E4 + (tx ^ k4);
#pragma unroll
                for (int m = 0; m < 4; m++) {
                    const int k = k4 * 4 + m;
                    float4 a0 = Aty[k * 32];
                    float4 a1 = Aty[k * 32 + 1];
                    float4 e0 = Ee[k * 32];
                    float4 e1 = Ee[k * 32 + 16];
                    float av[8] = {a0.x, a0.y, a0.z, a0.w, a1.x, a1.y, a1.z, a1.w};
                    float ev[8] = {e0.x, e0.y, e0.z, e0.w, e1.x, e1.y, e1.z, e1.w};
#pragma unroll
                    for (int i = 0; i < 8; i++)
#pragma unroll
                        for (int j = 0; j < 8; j++)
                            acc[i][j] = fmaf(av[i], ev[j], acc[i][j]);
                }
            }
        } else {
#pragma unroll 2
            for (int k4 = 0; k4 < 8; k4++) {
                const float4* Ee = E4 + (tx ^ k4);
#pragma unroll
                for (int m = 0; m < 4; m++) {
                    const int k = k4 * 4 + m;
                    float4 a0 = Aty[k * 32];
                    float4 a1 = Aty[k * 32 + 1];
                    float4 e0 = Ee[k * 32];
                    float av[8] = {a0.x, a0.y, a0.z, a0.w, a1.x, a1.y, a1.z, a1.w};
                    float ev[4] = {e0.x, e0.y, e0.z, e0.w};
#pragma unroll
                    for (int i = 0; i < 8; i++)
#pragma unroll
                        for (int j = 0; j < 4; j++)
                            acc[i][j] = fmaf(av[i], ev[j], acc[i][j]);
                }
            }
        }
    }
    if (tid < 128) zsqs[tid] = (float)zacc;
    __syncthreads();
    float zs[8];
#pragma unroll
    for (int i = 0; i < 8; i++) zs[i] = zsqs[ty * 8 + i];

    // local fold (ascending v, strict <): d2 = fl(fl(zsq - 2*dot) + esq)
    float br[8]; int bv[8];
#pragma unroll
    for (int i = 0; i < 8; i++) { br[i] = 3.0e38f; bv[i] = 0; }
    if (full) {
        float esql[8];
#pragma unroll
        for (int j = 0; j < 4; j++) esql[j] = ws[OFF_ESQ + (size_t)(vbase + tx * 4 + j) * 2 + g];
#pragma unroll
        for (int j = 4; j < 8; j++) esql[j] = ws[OFF_ESQ + (size_t)(vbase + 64 + tx * 4 + (j - 4)) * 2 + g];
#pragma unroll
        for (int i = 0; i < 8; i++)
#pragma unroll
            for (int j = 0; j < 8; j++) {
                float t = zs[i] - 2.0f * acc[i][j];
                float d2 = t + esql[j];
                int v = (j < 4) ? (vbase + tx * 4 + j) : (vbase + 64 + tx * 4 + (j - 4));
                if (d2 < br[i]) { br[i] = d2; bv[i] = v; }
            }
    } else {
        float esql[4];
#pragma unroll
        for (int j = 0; j < 4; j++) esql[j] = ws[OFF_ESQ + (size_t)(256 + tx * 4 + j) * 2 + g];
#pragma unroll
        for (int i = 0; i < 8; i++)
#pragma unroll
            for (int j = 0; j < 4; j++) {
                float t = zs[i] - 2.0f * acc[i][j];
                float d2 = t + esql[j];
                int v = 256 + tx * 4 + j;
                if (d2 < br[i]) { br[i] = d2; bv[i] = v; }
            }
    }

    // cross-thread (tx) lexicographic min, 16-wide shfl
#pragma unroll
    for (int i = 0; i < 8; i++) {
#pragma unroll
        for (int off = 8; off; off >>= 1) {
            float r2 = __shfl_down(br[i], off, 16);
            int v2 = __shfl_down(bv[i], off, 16);
            if (r2 < br[i] || (r2 == br[i] && v2 < bv[i])) { br[i] = r2; bv[i] = v2; }
        }
    }
    if (tx == 0) {
        unsigned long long* keys = (unsigned long long*)(ws + KEY_OFF);
#pragma unroll
        for (int i = 0; i < 8; i++) {
            const int tok = ty * 8 + i;
            atomicMin(&keys[(size_t)(tok0 + tok) * 2 + g], packkey(br[i], bv[i]));
        }
    }
}

// unpack winners: idx floats, histogram, loss sum. 64 blocks x 256 thr x 4 keys.
__global__ __launch_bounds__(256) void k_post(float* out, float* ws) {
    __shared__ int shist[640];
    __shared__ float wsum[4];
    const int tid = threadIdx.x;
    const unsigned long long* keys = (const unsigned long long*)(ws + KEY_OFF);
    int* hist = ((int*)ws) + OFF_HIST;
    for (int i = tid; i < 640; i += 256) shist[i] = 0;
    __syncthreads();
    float lsum = 0.0f;
#pragma unroll
    for (int r = 0; r < 4; r++) {
        const int i = blockIdx.x * 1024 + r * 256 + tid;   // i = tok*2+g
        unsigned long long key = keys[i];
        unsigned v = (unsigned)(key & 0xFFFFFFFFu);
        unsigned u = (unsigned)(key >> 32);
        unsigned bits = (u & 0x80000000u) ? (u ^ 0x80000000u) : ~u;
        float d2 = __uint_as_float(bits);
        const int g = i & 1;
        out[IDX_OFF + i] = (float)v;
        atomicAdd(&shist[g * 320 + (int)v], 1);
        lsum += d2;
    }
    for (int off = 32; off; off >>= 1) lsum += __shfl_down(lsum, off);
    if ((tid & 63) == 0) wsum[tid >> 6] = lsum;
    __syncthreads();
    if (tid == 0) atomicAdd(&ws[OFF_LOSS], wsum[0] + wsum[1] + wsum[2] + wsum[3]);
    for (int i = tid; i < 640; i += 256) atomicAdd(&hist[i], shist[i]);
}

// FALLBACK (ws too small for keys): round-5 proven in-block 2.5-pass VQ (196us).
__global__ __launch_bounds__(256, 2) void k_vq_fb(const float* __restrict__ emb,
                                                  const float* __restrict__ gnw,
                                                  const float* __restrict__ gnb,
                                                  float* out, float* ws) {
    __shared__ float As[64 * 128];   // LINEAR [k][tok]   32 KB
    __shared__ float Es[64 * 128];   // swizzled [k][v]   32 KB
    __shared__ float Gw[256];
    __shared__ float Gb[256];
    __shared__ float zsqs[128];
    __shared__ float lsum[16];

    const int tid = threadIdx.x;
    const int tx = tid & 15, ty = tid >> 4;
    const int tok0 = blockIdx.x * 128;
    const int g = blockIdx.y;
    const int b = tok0 >> 11;
    const float mu = ws[OFF_MU + b * 2 + g];
    const float rstd = ws[OFF_RSTD + b * 2 + g];
    int* hist = ((int*)ws) + OFF_HIST;
    const float* yt = out;

    Gw[tid] = gnw[g * VDIM + tid];
    Gb[tid] = gnb[g * VDIM + tid];

    const int skr = tid >> 5;
    const int st4 = tid & 31;
    const float* ybase = yt + ((size_t)g * 256 + skr) * NTOK + tok0 + st4 * 4;

    float br[8]; int bv[8]; float zs[8];
#pragma unroll
    for (int i = 0; i < 8; i++) { br[i] = 3.0e38f; bv[i] = 0; }
    double zacc = 0.0;
    float4 pv[8];

#define LOADY(KC) do {                                                         \
    _Pragma("unroll")                                                          \
    for (int it_ = 0; it_ < 8; it_++)                                          \
        pv[it_] = *(const float4*)(ybase + (size_t)((KC) * 64 + it_ * 8) * NTOK); \
} while (0)

#define WRITE_AS(KC) do {                                                      \
    _Pragma("unroll")                                                          \
    for (int it_ = 0; it_ < 8; it_++) {                                        \
        const int kl_ = it_ * 8 + skr;                                         \
        const float gw_ = Gw[(KC) * 64 + kl_];                                 \
        const float gb_ = Gb[(KC) * 64 + kl_];                                 \
        float4 v_ = pv[it_];                                                   \
        float4 z_;                                                             \
        z_.x = fmaf((v_.x - mu) * rstd, gw_, gb_);                             \
        z_.y = fmaf((v_.y - mu) * rstd, gw_, gb_);                             \
        z_.z = fmaf((v_.z - mu) * rstd, gw_, gb_);                             \
        z_.w = fmaf((v_.w - mu) * rstd, gw_, gb_);                             \
        ((float4*)As)[it_ * 256 + tid] = z_;                                   \
    }                                                                          \
} while (0)

    for (int pass = 0; pass < 2; pass++) {
        const int vbase = pass * 128;
        float acc[8][8];
#pragma unroll
        for (int i = 0; i < 8; i++)
#pragma unroll
            for (int j = 0; j < 8; j++) acc[i][j] = 0.0f;

        LOADY(0);
        for (int kc = 0; kc < 4; kc++) {
            __syncthreads();
            WRITE_AS(kc);
#pragma unroll
            for (int it = 0; it < 8; it++) {
                const int vr = ty + 16 * it;
                float4 e = *(const float4*)(emb + (size_t)((vbase + vr) * 2 + g) * VDIM + kc * 64 + tx * 4);
                Es[sw128(tx * 4 + 0, vr)] = e.x; Es[sw128(tx * 4 + 1, vr)] = e.y;
                Es[sw128(tx * 4 + 2, vr)] = e.z; Es[sw128(tx * 4 + 3, vr)] = e.w;
            }
            if (kc < 3) LOADY(kc + 1);
            __syncthreads();
            if (pass == 0 && tid < 128) {
                for (int k = 0; k < 64; k++) {
                    float z = As[k * 128 + tid];
                    zacc += (double)z * z;
                }
            }
            const float4* Aty = ((const float4*)As) + 2 * ty;
            const float4* E4 = (const float4*)Es;
#pragma unroll 2
            for (int k4 = 0; k4 < 16; k4++) {
                const float4* Ee = E4 + (tx ^ k4);
#pragma unroll
                for (int m = 0; m < 4; m++) {
                    const int k = k4 * 4 + m;
                    float4 a0 = Aty[k * 32];
                    float4 a1 = Aty[k * 32 + 1];
                    float4 e0 = Ee[k * 32];
                    float4 e1 = Ee[k * 32 + 16];
                    float av[8] = {a0.x, a0.y, a0.z, a0.w, a1.x, a1.y, a1.z, a1.w};
                    float ev[8] = {e0.x, e0.y, e0.z, e0.w, e1.x, e1.y, e1.z, e1.w};
#pragma unroll
                    for (int i = 0; i < 8; i++)
#pragma unroll
                        for (int j = 0; j < 8; j++)
                            acc[i][j] = fmaf(av[i], ev[j], acc[i][j]);
                }
            }
        }
        if (pass == 0) {
            if (tid < 128) zsqs[tid] = (float)zacc;
            __syncthreads();
#pragma unroll
            for (int i = 0; i < 8; i++) zs[i] = zsqs[ty * 8 + i];
        }
        float esql[8];
#pragma unroll
        for (int j = 0; j < 4; j++) esql[j] = ws[OFF_ESQ + (size_t)(vbase + tx * 4 + j) * 2 + g];
#pragma unroll
        for (int j = 4; j < 8; j++) esql[j] = ws[OFF_ESQ + (size_t)(vbase + 64 + tx * 4 + (j - 4)) * 2 + g];
#pragma unroll
        for (int i = 0; i < 8; i++)
#pragma unroll
            for (int j = 0; j < 8; j++) {
                float t = zs[i] - 2.0f * acc[i][j];
                float d2 = t + esql[j];
                int v = (j < 4) ? (vbase + tx * 4 + j) : (vbase + 64 + tx * 4 + (j - 4));
                if (d2 < br[i]) { br[i] = d2; bv[i] = v; }
            }
    }
    {
        float acc[8][4];
#pragma unroll
        for (int i = 0; i < 8; i++)
#pragma unroll
            for (int j = 0; j < 4; j++) acc[i][j] = 0.0f;

        LOADY(0);
        for (int kc = 0; kc < 4; kc++) {
            __syncthreads();
            WRITE_AS(kc);
#pragma unroll
            for (int it = 0; it < 4; it++) {
                const int vr = ty + 16 * it;
                float4 e = *(const float4*)(emb + (size_t)((256 + vr) * 2 + g) * VDIM + kc * 64 + tx * 4);
                Es[sw128(tx * 4 + 0, vr)] = e.x; Es[sw128(tx * 4 + 1, vr)] = e.y;
                Es[sw128(tx * 4 + 2, vr)] = e.z; Es[sw128(tx * 4 + 3, vr)] = e.w;
            }
            if (kc < 3) LOADY(kc + 1);
            __syncthreads();
            const float4* Aty = ((const float4*)As) + 2 * ty;
            const float4* E4 = (const float4*)Es;
#pragma unroll 2
            for (int k4 = 0; k4 < 16; k4++) {
                const float4* Ee = E4 + (tx ^ k4);
#pragma unroll
                for (int m = 0; m < 4; m++) {
                    const int k = k4 * 4 + m;
                    float4 a0 = Aty[k * 32];
                    float4 a1 = Aty[k * 32 + 1];
                    float4 e0 = Ee[k * 32];
                    float av[8] = {a0.x, a0.y, a0.z, a0.w, a1.x, a1.y, a1.z, a1.w};
                    float ev[4] = {e0.x, e0.y, e0.z, e0.w};
#pragma unroll
                    for (int i = 0; i < 8; i++)
#pragma unroll
                        for (int j = 0; j < 4; j++)
                            acc[i][j] = fmaf(av[i], ev[j], acc[i][j]);
                }
            }
        }
        float esql[4];
#pragma unroll
        for (int j = 0; j < 4; j++) esql[j] = ws[OFF_ESQ + (size_t)(256 + tx * 4 + j) * 2 + g];
#pragma unroll
        for (int i = 0; i < 8; i++)
#pragma unroll
            for (int j = 0; j < 4; j++) {
                float t = zs[i] - 2.0f * acc[i][j];
                float d2 = t + esql[j];
                int v = 256 + tx * 4 + j;
                if (d2 < br[i]) { br[i] = d2; bv[i] = v; }
            }
    }
#undef LOADY
#undef WRITE_AS

#pragma unroll
    for (int i = 0; i < 8; i++) {
#pragma unroll
        for (int off = 8; off; off >>= 1) {
            float r2 = __shfl_down(br[i], off, 16);
            int v2 = __shfl_down(bv[i], off, 16);
            if (r2 < br[i] || (r2 == br[i] && v2 < bv[i])) { br[i] = r2; bv[i] = v2; }
        }
    }
    float dlocal = 0.0f;
    if (tx == 0) {
#pragma unroll
        for (int i = 0; i < 8; i++) {
            const int tok = ty * 8 + i;
            out[IDX_OFF + (size_t)(tok0 + tok) * 2 + g] = (float)bv[i];
            atomicAdd(&hist[g * 320 + bv[i]], 1);
            dlocal += br[i];
        }
        lsum[ty] = dlocal;
    }
    __syncthreads();
    if (tid == 0) {
        float s = 0.0f;
        for (int t = 0; t < 16; t++) s += lsum[t];
        atomicAdd(&ws[OFF_LOSS], s);
    }
}

// x_out = zq gather: reads idx from out's idx region, overwrites y_t region with zq.
__global__ __launch_bounds__(256) void k_gather(const float* __restrict__ emb,
                                                float* out) {
    __shared__ int sidx[128];
    const int tid = threadIdx.x;
    const int tok0 = blockIdx.x * 64;
    if (tid < 128) sidx[tid] = (int)out[IDX_OFF + (size_t)tok0 * 2 + tid];
    __syncthreads();
#pragma unroll 4
    for (int it = 0; it < 32; it++) {
        const int j = it * 256 + tid;
        const int tl = j >> 7;           // token within block (0..63)
        const int c4 = j & 127;          // float4 index within row (0..127)
        const int g = c4 >> 6;
        const int v = sidx[tl * 2 + g];
        float4 e = *(const float4*)(emb + (size_t)(v * 2 + g) * VDIM + (c4 & 63) * 4);
        *(float4*)(out + (size_t)(tok0 + tl) * DIMC + c4 * 4) = e;
    }
}

__global__ void k_final(float* out, float* ws) {
    __shared__ float red[512];
    int tid = threadIdx.x;
    int* hist = ((int*)ws) + OFF_HIST;
    float ppl = 0.0f;
    for (int g = 0; g < 2; g++) {
        float term = 0.0f;
        if (tid < 320) {
            float p = (float)hist[g * 320 + tid] * (1.0f / 32768.0f);
            term = p * logf(p + 1e-7f);
        }
        red[tid] = term;
        __syncthreads();
        for (int s = 256; s; s >>= 1) {
            if (tid < s) red[tid] += red[tid + s];
            __syncthreads();
        }
        if (tid == 0) ppl += expf(-red[0]);
        __syncthreads();
    }
    if (tid == 0) {
        out[PPL_OFF] = ppl;
        out[KM_OFF] = 1.25f * ws[OFF_LOSS] / 16777216.0f;
    }
}

extern "C" void kernel_launch(void* const* d_in, const int* in_sizes, int n_in,
                              void* d_out, int out_size, void* d_ws, size_t ws_size,
                              hipStream_t stream) {
    (void)in_sizes; (void)n_in; (void)out_size;
    const float* x      = (const float*)d_in[0];
    const float* conv_w = (const float*)d_in[1];
    const float* gn_w   = (const float*)d_in[2];
    const float* gn_b   = (const float*)d_in[3];
    const float* emb    = (const float*)d_in[4];
    float* out = (float*)d_out;
    float* ws  = (float*)d_ws;
    const bool big_ws = (ws_size == 0) || (ws_size >= WS_NEED_BYTES);

    if (big_ws) {
        hipLaunchKernelGGL(k_init2, dim3(256),       dim3(256), 0, stream, ws);
        hipLaunchKernelGGL(k_esq,   dim3(160),       dim3(256), 0, stream, emb, ws);
        hipLaunchKernelGGL(k_gemm,  dim3(256, 2, 2), dim3(256), 0, stream, x, conv_w, out, ws);
        hipLaunchKernelGGL(k_stats, dim3(1),         dim3(64),  0, stream, ws);
        hipLaunchKernelGGL(k_vq,    dim3(256, 2, 3), dim3(256), 0, stream, emb, gn_w, gn_b, out, ws);
        hipLaunchKernelGGL(k_post,  dim3(64),        dim3(256), 0, stream, out, ws);
    } else {
        hipLaunchKernelGGL(k_init,  dim3(7),         dim3(256), 0, stream, ws);
        hipLaunchKernelGGL(k_esq,   dim3(160),       dim3(256), 0, stream, emb, ws);
        hipLaunchKernelGGL(k_gemm,  dim3(256, 2, 2), dim3(256), 0, stream, x, conv_w, out, ws);
        hipLaunchKernelGGL(k_stats, dim3(1),         dim3(64),  0, stream, ws);
        hipLaunchKernelGGL(k_vq_fb, dim3(256, 2),    dim3(256), 0, stream, emb, gn_w, gn_b, out, ws);
    }
    hipLaunchKernelGGL(k_gather, dim3(512), dim3(256), 0, stream, emb, out);
    hipLaunchKernelGGL(k_final,  dim3(1),   dim3(512), 0, stream, out, ws);
}